// Round 9
// baseline (251.549 us; speedup 1.0000x reference)
//
#include <hip/hip_runtime.h>

#define TSTEPS 8192
#define HDIM 4096
#define PDIM 4
#define KDIM 64

typedef unsigned short u16;
typedef __attribute__((ext_vector_type(8))) short short8;
typedef __attribute__((ext_vector_type(4))) float f32x4;

#define S1 -1.44269504089f   // -log2(e)
#define S2 -2.88539008177f   // -2*log2(e)

#if __has_builtin(__builtin_amdgcn_exp2f)
#define EXP2(x) __builtin_amdgcn_exp2f(x)
#else
#define EXP2(x) exp2f(x)
#endif
__device__ __forceinline__ float rcpf(float x) { return __builtin_amdgcn_rcpf(x); }

// tanh(c)*sig(o) for c in (-1,1), given ec = e^-o. Pade CF-7 tanh (err ~5e-6)
// merged into sig's rcp: saves one transcendental vs exp-based tanh.
__device__ __forceinline__ float h_merge(float c, float ec) {
  float c2 = c * c;
  float num = c * fmaf(c2, 10.0f, 105.0f);
  float den = fmaf(c2, 45.0f, 105.0f) + c2 * c2;
  return num * rcpf(den * (1.0f + ec));
}

// async global->LDS DMA, 16B per lane; LDS dest = uniform base + lane*16
__device__ __forceinline__ void gload16(const void* g, void* l) {
  __builtin_amdgcn_global_load_lds((const __attribute__((address_space(1))) unsigned int*)g,
                                   (__attribute__((address_space(3))) unsigned int*)l,
                                   16, 0, 0);
}

__device__ __forceinline__ u16 bf16_rne(float f) {
  unsigned u = __float_as_uint(f);
  u += 0x7FFF + ((u >> 16) & 1);
  return (u16)(u >> 16);
}
__device__ __forceinline__ void hilo(float v, u16& h, u16& l) {
  h = bf16_rne(v);
  l = bf16_rne(v - __uint_as_float((unsigned)h << 16));
}

// ---- workspace layout (float offsets) ----
#define WS_Y0   0
#define WS_Y1   32768
#define WS_BSC  65536
#define WS_C1   77824
#define WS_C2   159744
#define WS_XHI  241664
#define WS_XLO  503808
#define WS_WHI  765952
#define WS_WLO  1159168
#define WS_PP   1552384
// total 3649536 floats = 14.6 MB

// One-shot prep: bf16 hi/lo of x and W_ih0 (i,g,o rows, PRE-SCALED by S1/S2 so
// gates feed v_exp directly), scaled merged biases, packed per-j records for
// layers 1/2.
__global__ void prep_kernel(const float* __restrict__ x,
                            const float* __restrict__ Wih0, const float* __restrict__ bih0,
                            const float* __restrict__ bhh0,
                            const float* __restrict__ Wih1, const float* __restrict__ bih1,
                            const float* __restrict__ bhh1, const float* __restrict__ Whr1,
                            const float* __restrict__ Wih2, const float* __restrict__ bih2,
                            const float* __restrict__ bhh2, const float* __restrict__ Whr2,
                            float* __restrict__ ws) {
  const int i = blockIdx.x * 256 + threadIdx.x;
  u16* xhi = (u16*)(ws + WS_XHI);
  u16* xlo = (u16*)(ws + WS_XLO);
  u16* whi = (u16*)(ws + WS_WHI);
  u16* wlo = (u16*)(ws + WS_WLO);

  if (i < 131072) {                       // x: 131072 float4 units, unscaled
    float4 v = *(const float4*)&x[i * 4];
    float val[4] = {v.x, v.y, v.z, v.w};
    u16 h[4], l[4];
#pragma unroll
    for (int e = 0; e < 4; ++e) hilo(val[e], h[e], l[e]);
    *(ushort4*)&xhi[i * 4] = make_ushort4(h[0], h[1], h[2], h[3]);
    *(ushort4*)&xlo[i * 4] = make_ushort4(l[0], l[1], l[2], l[3]);
  } else if (i < 327680) {                // W_ih0: 196608 float4 units, scaled
    int f = i - 131072;
    int el4 = f * 4;
    int r = el4 >> 6;                     // packed row 0..12287 ([gate][j])
    int k4 = el4 & 63;
    int gate = r >> 12, jr = r & 4095;
    int src = (gate == 0) ? jr : (gate + 1) * HDIM + jr;   // i,g,o = rows 0,2H,3H
    float sc = (gate == 1) ? S2 : S1;
    float4 v = *(const float4*)&Wih0[(size_t)src * KDIM + k4];
    float val[4] = {sc * v.x, sc * v.y, sc * v.z, sc * v.w};
    u16 h[4], l[4];
#pragma unroll
    for (int e = 0; e < 4; ++e) hilo(val[e], h[e], l[e]);
    *(ushort4*)&whi[r * KDIM + k4] = make_ushort4(h[0], h[1], h[2], h[3]);
    *(ushort4*)&wlo[r * KDIM + k4] = make_ushort4(l[0], l[1], l[2], l[3]);
  } else if (i < 339968) {                // bsc[3][4096], scaled merged bias
    int f = i - 327680;
    int g = f >> 12, j = f & 4095;
    int src = (g == 0) ? j : (g + 1) * HDIM + j;
    float sc = (g == 1) ? S2 : S1;
    ws[WS_BSC + f] = sc * (bih0[src] + bhh0[src]);
  } else if (i < 348160) {                // c1/c2 packed records (20 floats/j)
    int f = i - 339968;
    const float* Wih = (f < 4096) ? Wih1 : Wih2;
    const float* bih = (f < 4096) ? bih1 : bih2;
    const float* bhh = (f < 4096) ? bhh1 : bhh2;
    const float* Whr = (f < 4096) ? Whr1 : Whr2;
    float* c = ws + ((f < 4096) ? WS_C1 : WS_C2);
    int j = f & 4095;
    float4 wi = *(const float4*)&Wih[(size_t)j * 4];
    float4 wg = *(const float4*)&Wih[(size_t)(2 * HDIM + j) * 4];
    float4 wo = *(const float4*)&Wih[(size_t)(3 * HDIM + j) * 4];
    float* cb = c + j * 20;
    *(float4*)(cb + 0)  = make_float4(S1 * wi.x, S1 * wi.y, S1 * wi.z, S1 * wi.w);
    *(float4*)(cb + 4)  = make_float4(S2 * wg.x, S2 * wg.y, S2 * wg.z, S2 * wg.w);
    *(float4*)(cb + 8)  = make_float4(S1 * wo.x, S1 * wo.y, S1 * wo.z, S1 * wo.w);
    *(float4*)(cb + 12) = make_float4(S1 * (bih[j] + bhh[j]),
                                      S2 * (bih[2 * HDIM + j] + bhh[2 * HDIM + j]),
                                      S1 * (bih[3 * HDIM + j] + bhh[3 * HDIM + j]), 0.f);
    *(float4*)(cb + 16) = make_float4(Whr[j], Whr[HDIM + j], Whr[2 * HDIM + j], Whr[3 * HDIM + j]);
  }
}

// Layer 0: async-staged MFMA, register-dieted for 3 waves/SIMD.
// Block = 4 waves covering 64t x 64j: wave (jh=w>>1, th=w&1) owns 32t x 32j.
// acc[2][2][3] = 48 AGPR (js=2); x hi/lo fragments global->VGPR (32 regs);
// only W in LDS: 48KB swizzled + 2KB reduce buf = 50KB -> 3 blocks/CU.
// Total regs ~125 < 170 -> 3 waves/SIMD (vs r8's 224 -> 2).
// Grid = 128 tbb x 64 jb = 8192. ONE DMA barrier; butterfly proj over the
// 16 m-lanes; cross-wave (jh) sum via 2KB LDS; pp stays at 64 slices.
__global__ __launch_bounds__(256, 3)
void lstm_layer0_mfma(const u16* __restrict__ xhi, const u16* __restrict__ xlo,
                      const u16* __restrict__ whi, const u16* __restrict__ wlo,
                      const float* __restrict__ bsc, const float* __restrict__ Whr,
                      float* __restrict__ pp) {
  __shared__ __align__(16) char smem[51200];      // 48K W + 2K reduce
  u16* lw_hi = (u16*)smem;                        // rows g*64+jj, swizzled
  u16* lw_lo = (u16*)(smem + 24576);
  float* red = (float*)(smem + 49152);            // [2 jh][64 t][4 p]

  const int tid = threadIdx.x;
  const int w = tid >> 6, lane = tid & 63;
  const int m = lane & 15, q = lane >> 4;
  const int th = w & 1, jh = w >> 1;
  const int jb = blockIdx.x & 63, tbb = blockIdx.x >> 6;
  const int j0 = jb * 64;
  const int t0 = tbb * 64;

  const int r8_ = lane >> 3;
  const int swo = ((lane & 7) ^ r8_) * 8;

  // ---- stage W: 48 x 1KB units (24 hi + 24 lo), 12 per wave
#pragma unroll
  for (int ui = 0; ui < 12; ++ui) {
    const int u = w * 12 + ui;
    const u16* g;
    if (u < 24) {
      int row = u * 8 + r8_;
      g = whi + (size_t)((row >> 6) * HDIM + j0 + (row & 63)) * 64 + swo;
    } else {
      int row = (u - 24) * 8 + r8_;
      g = wlo + (size_t)((row >> 6) * HDIM + j0 + (row & 63)) * 64 + swo;
    }
    gload16(g, smem + u * 1024);
  }

  // ---- x fragments global->VGPR (issue early; overlap DMA)
  short8 ah[2][2], al[2][2];
#pragma unroll
  for (int kc = 0; kc < 2; ++kc)
#pragma unroll
    for (int ts = 0; ts < 2; ++ts) {
      size_t ax = (size_t)(t0 + th * 32 + ts * 16 + m) * KDIM + kc * 32 + q * 8;
      ah[kc][ts] = *(const short8*)&xhi[ax];
      al[kc][ts] = *(const short8*)&xlo[ax];
    }

  // per-lane epilogue constants (L2-hot scalar-ish loads)
  float whr_v[4][2], biv[2], bgv[2], bov[2];
#pragma unroll
  for (int js = 0; js < 2; ++js) {
    const int j = j0 + jh * 32 + js * 16 + m;
#pragma unroll
    for (int p = 0; p < 4; ++p) whr_v[p][js] = Whr[(size_t)p * HDIM + j];
    biv[js] = bsc[j];
    bgv[js] = bsc[HDIM + j];
    bov[js] = bsc[2 * HDIM + j];
  }

  f32x4 acc[2][2][3];
#pragma unroll
  for (int ts = 0; ts < 2; ++ts)
#pragma unroll
    for (int js = 0; js < 2; ++js)
#pragma unroll
      for (int g = 0; g < 3; ++g) acc[ts][js][g] = (f32x4){0.f, 0.f, 0.f, 0.f};

  __syncthreads();   // drain W DMA

  // ---- MFMA burst: 72 MFMA / 24 b128 LDS reads per wave
#pragma unroll
  for (int kc = 0; kc < 2; ++kc) {
    const int cs = ((kc * 4 + q) ^ (m & 7)) * 8;
#pragma unroll
    for (int js = 0; js < 2; ++js) {
#pragma unroll
      for (int g = 0; g < 3; ++g) {
        const int roff = (g * 64 + jh * 32 + js * 16 + m) * 64 + cs;
        short8 bh = *(const short8*)&lw_hi[roff];
        short8 bl = *(const short8*)&lw_lo[roff];
#pragma unroll
        for (int ts = 0; ts < 2; ++ts) {
          acc[ts][js][g] = __builtin_amdgcn_mfma_f32_16x16x32_bf16(ah[kc][ts], bh, acc[ts][js][g], 0, 0, 0);
          acc[ts][js][g] = __builtin_amdgcn_mfma_f32_16x16x32_bf16(al[kc][ts], bh, acc[ts][js][g], 0, 0, 0);
          acc[ts][js][g] = __builtin_amdgcn_mfma_f32_16x16x32_bf16(ah[kc][ts], bl, acc[ts][js][g], 0, 0, 0);
        }
      }
    }
  }

  // ---- activations + projection, streamed per (ts,r) to keep regs low
#pragma unroll
  for (int ts = 0; ts < 2; ++ts) {
#pragma unroll
    for (int r = 0; r < 4; ++r) {
      float pv[4] = {0.f, 0.f, 0.f, 0.f};
#pragma unroll
      for (int js = 0; js < 2; ++js) {
        float ea = EXP2(acc[0 * 2 + ts >= 2 ? 1 : ts][js][0][r] + biv[js]); // (ts)
        float eb = EXP2(acc[ts][js][1][r] + bgv[js]);
        float c = (1.0f - eb) * rcpf((1.0f + ea) * (1.0f + eb));   // sig(i)tanh(g)
        float ec = EXP2(acc[ts][js][2][r] + bov[js]);
        float h = h_merge(c, ec);                                  // tanh(c)sig(o)
#pragma unroll
        for (int p = 0; p < 4; ++p) pv[p] = fmaf(h, whr_v[p][js], pv[p]);
      }
#pragma unroll
      for (int p = 0; p < 4; ++p) {
#pragma unroll
        for (int ofs = 1; ofs < 16; ofs <<= 1) pv[p] += __shfl_xor(pv[p], ofs, 16);
      }
      if (m == 0) {
        const int tl = th * 32 + ts * 16 + q * 4 + r;
        *(float4*)&red[(jh * 64 + tl) * 4] = make_float4(pv[0], pv[1], pv[2], pv[3]);
      }
    }
  }
  __syncthreads();

  // cross-wave (jh) sum; 256 consecutive floats -> coalesced store
  float s = red[tid] + red[256 + tid];
  pp[(size_t)jb * (TSTEPS * PDIM) + t0 * PDIM + tid] = s;
}

// Reduce 64 partial slices -> y[t][4]; one thread per (t,p), fully coalesced.
__global__ void reduce64(const float* __restrict__ pp, float* __restrict__ y) {
  const int i = blockIdx.x * 256 + threadIdx.x;   // 0..32767 = t*4 + p
  float s = 0.f;
#pragma unroll 16
  for (int k = 0; k < 64; ++k) s += pp[(size_t)k * (TSTEPS * PDIM) + i];
  y[i] = s;
}

// Layers 1-2 (K=4): LDS-staged records amortized over 2 timesteps/thread
// (2.5 b128 per h instead of 5 -> VALU-bound, not LDS-bound) + Pade tanh.
// Grid = 16 tchunks x 64 jsplits = 1024 -> 4 blocks/CU, bounds (256,4).
__global__ __launch_bounds__(256, 4)
void lstm_small(const float* __restrict__ xin, const float* __restrict__ cpk,
                float* __restrict__ pp) {
  __shared__ __align__(16) float rec[1280];       // 64 records x 20 floats
  const int tid = threadIdx.x;
  const int tc = blockIdx.x >> 6;                 // 0..15
  const int jsp = blockIdx.x & 63;                // 0..63
  const int j0 = jsp * 64;

  for (int i = tid; i < 320; i += 256)
    ((float4*)rec)[i] = ((const float4*)(cpk + (size_t)j0 * 20))[i];

  const int ta = tc * 512 + tid;
  const int tb2 = ta + 256;
  float4 xa = ((const float4*)xin)[ta];
  float4 xb = ((const float4*)xin)[tb2];
  float a0 = 0.f, a1 = 0.f, a2 = 0.f, a3 = 0.f;
  float b0 = 0.f, b1 = 0.f, b2 = 0.f, b3 = 0.f;
  __syncthreads();

#pragma unroll 4
  for (int jj = 0; jj < 64; ++jj) {
    const float* cb = rec + jj * 20;
    float4 wi = *(const float4*)(cb + 0);
    float4 wg = *(const float4*)(cb + 4);
    float4 wo = *(const float4*)(cb + 8);
    float4 bb = *(const float4*)(cb + 12);
    float4 wr = *(const float4*)(cb + 16);
    // timestep a
    float gi = bb.x, gg = bb.y, go = bb.z;
    gi = fmaf(xa.x, wi.x, gi); gi = fmaf(xa.y, wi.y, gi);
    gi = fmaf(xa.z, wi.z, gi); gi = fmaf(xa.w, wi.w, gi);
    gg = fmaf(xa.x, wg.x, gg); gg = fmaf(xa.y, wg.y, gg);
    gg = fmaf(xa.z, wg.z, gg); gg = fmaf(xa.w, wg.w, gg);
    go = fmaf(xa.x, wo.x, go); go = fmaf(xa.y, wo.y, go);
    go = fmaf(xa.z, wo.z, go); go = fmaf(xa.w, wo.w, go);
    float ea = EXP2(gi), eb = EXP2(gg);
    float c = (1.0f - eb) * rcpf((1.0f + ea) * (1.0f + eb));
    float h = h_merge(c, EXP2(go));
    a0 = fmaf(h, wr.x, a0); a1 = fmaf(h, wr.y, a1);
    a2 = fmaf(h, wr.z, a2); a3 = fmaf(h, wr.w, a3);
    // timestep b
    gi = bb.x; gg = bb.y; go = bb.z;
    gi = fmaf(xb.x, wi.x, gi); gi = fmaf(xb.y, wi.y, gi);
    gi = fmaf(xb.z, wi.z, gi); gi = fmaf(xb.w, wi.w, gi);
    gg = fmaf(xb.x, wg.x, gg); gg = fmaf(xb.y, wg.y, gg);
    gg = fmaf(xb.z, wg.z, gg); gg = fmaf(xb.w, wg.w, gg);
    go = fmaf(xb.x, wo.x, go); go = fmaf(xb.y, wo.y, go);
    go = fmaf(xb.z, wo.z, go); go = fmaf(xb.w, wo.w, go);
    ea = EXP2(gi); eb = EXP2(gg);
    c = (1.0f - eb) * rcpf((1.0f + ea) * (1.0f + eb));
    h = h_merge(c, EXP2(go));
    b0 = fmaf(h, wr.x, b0); b1 = fmaf(h, wr.y, b1);
    b2 = fmaf(h, wr.z, b2); b3 = fmaf(h, wr.w, b3);
  }

  ((float4*)pp)[(size_t)jsp * TSTEPS + ta]  = make_float4(a0, a1, a2, a3);
  ((float4*)pp)[(size_t)jsp * TSTEPS + tb2] = make_float4(b0, b1, b2, b3);
}

extern "C" void kernel_launch(void* const* d_in, const int* in_sizes, int n_in,
                              void* d_out, int out_size, void* d_ws, size_t ws_size,
                              hipStream_t stream) {
  const float* x    = (const float*)d_in[0];
  const float* Wih0 = (const float*)d_in[1];
  const float* bih0 = (const float*)d_in[3];
  const float* bhh0 = (const float*)d_in[4];
  const float* Whr0 = (const float*)d_in[5];
  const float* Wih1 = (const float*)d_in[6];
  const float* bih1 = (const float*)d_in[8];
  const float* bhh1 = (const float*)d_in[9];
  const float* Whr1 = (const float*)d_in[10];
  const float* Wih2 = (const float*)d_in[11];
  const float* bih2 = (const float*)d_in[13];
  const float* bhh2 = (const float*)d_in[14];
  const float* Whr2 = (const float*)d_in[15];
  float* out = (float*)d_out;
  float* ws = (float*)d_ws;
  float* pp = ws + WS_PP;

  prep_kernel<<<dim3(1360), dim3(256), 0, stream>>>(
      x, Wih0, bih0, bhh0, Wih1, bih1, bhh1, Whr1, Wih2, bih2, bhh2, Whr2, ws);

  lstm_layer0_mfma<<<dim3(8192), dim3(256), 0, stream>>>(
      (const u16*)(ws + WS_XHI), (const u16*)(ws + WS_XLO),
      (const u16*)(ws + WS_WHI), (const u16*)(ws + WS_WLO),
      ws + WS_BSC, Whr0, pp);
  reduce64<<<dim3(128), dim3(256), 0, stream>>>(pp, ws + WS_Y0);

  lstm_small<<<dim3(1024), dim3(256), 0, stream>>>(ws + WS_Y0, ws + WS_C1, pp);
  reduce64<<<dim3(128), dim3(256), 0, stream>>>(pp, ws + WS_Y1);

  lstm_small<<<dim3(1024), dim3(256), 0, stream>>>(ws + WS_Y1, ws + WS_C2, pp);
  reduce64<<<dim3(128), dim3(256), 0, stream>>>(pp, out);
}

// Round 10
// 237.428 us; speedup vs baseline: 1.0595x; 1.0595x over previous
//
#include <hip/hip_runtime.h>

#define TSTEPS 8192
#define HDIM 4096
#define PDIM 4
#define KDIM 64

typedef unsigned short u16;
typedef __attribute__((ext_vector_type(8))) short short8;
typedef __attribute__((ext_vector_type(4))) float f32x4;

#define S1 -1.44269504089f   // -log2(e)
#define S2 -2.88539008177f   // -2*log2(e)

#if __has_builtin(__builtin_amdgcn_exp2f)
#define EXP2(x) __builtin_amdgcn_exp2f(x)
#else
#define EXP2(x) exp2f(x)
#endif
__device__ __forceinline__ float rcpf(float x) { return __builtin_amdgcn_rcpf(x); }

// tanh(c)*sig(o) for c in (-1,1), given ec = e^-o. Pade CF-7 tanh (err ~5e-6)
// merged into sig's rcp: one transcendental fewer than exp-based tanh.
__device__ __forceinline__ float h_merge(float c, float ec) {
  float c2 = c * c;
  float num = c * fmaf(c2, 10.0f, 105.0f);
  float den = fmaf(c2, 45.0f, 105.0f) + c2 * c2;
  return num * rcpf(den * (1.0f + ec));
}

// async global->LDS DMA, 16B per lane; LDS dest = uniform base + lane*16
__device__ __forceinline__ void gload16(const void* g, void* l) {
  __builtin_amdgcn_global_load_lds((const __attribute__((address_space(1))) unsigned int*)g,
                                   (__attribute__((address_space(3))) unsigned int*)l,
                                   16, 0, 0);
}

__device__ __forceinline__ u16 bf16_rne(float f) {
  unsigned u = __float_as_uint(f);
  u += 0x7FFF + ((u >> 16) & 1);
  return (u16)(u >> 16);
}
__device__ __forceinline__ void hilo(float v, u16& h, u16& l) {
  h = bf16_rne(v);
  l = bf16_rne(v - __uint_as_float((unsigned)h << 16));
}

// ---- workspace layout (float offsets) ----
#define WS_Y0   0
#define WS_Y1   32768
#define WS_BSC  65536
#define WS_C1   77824
#define WS_C2   159744
#define WS_XHI  241664
#define WS_XLO  503808
#define WS_WHI  765952
#define WS_WLO  1159168
#define WS_PP   1552384
// total 3649536 floats = 14.6 MB

// One-shot prep: bf16 hi/lo of x and W_ih0 (i,g,o rows, PRE-SCALED by S1/S2 so
// gates feed v_exp directly), scaled merged biases, packed per-j records for
// layers 1/2.
__global__ void prep_kernel(const float* __restrict__ x,
                            const float* __restrict__ Wih0, const float* __restrict__ bih0,
                            const float* __restrict__ bhh0,
                            const float* __restrict__ Wih1, const float* __restrict__ bih1,
                            const float* __restrict__ bhh1, const float* __restrict__ Whr1,
                            const float* __restrict__ Wih2, const float* __restrict__ bih2,
                            const float* __restrict__ bhh2, const float* __restrict__ Whr2,
                            float* __restrict__ ws) {
  const int i = blockIdx.x * 256 + threadIdx.x;
  u16* xhi = (u16*)(ws + WS_XHI);
  u16* xlo = (u16*)(ws + WS_XLO);
  u16* whi = (u16*)(ws + WS_WHI);
  u16* wlo = (u16*)(ws + WS_WLO);

  if (i < 131072) {                       // x: 131072 float4 units, unscaled
    float4 v = *(const float4*)&x[i * 4];
    float val[4] = {v.x, v.y, v.z, v.w};
    u16 h[4], l[4];
#pragma unroll
    for (int e = 0; e < 4; ++e) hilo(val[e], h[e], l[e]);
    *(ushort4*)&xhi[i * 4] = make_ushort4(h[0], h[1], h[2], h[3]);
    *(ushort4*)&xlo[i * 4] = make_ushort4(l[0], l[1], l[2], l[3]);
  } else if (i < 327680) {                // W_ih0: 196608 float4 units, scaled
    int f = i - 131072;
    int el4 = f * 4;
    int r = el4 >> 6;                     // packed row 0..12287 ([gate][j])
    int k4 = el4 & 63;
    int gate = r >> 12, jr = r & 4095;
    int src = (gate == 0) ? jr : (gate + 1) * HDIM + jr;   // i,g,o = rows 0,2H,3H
    float sc = (gate == 1) ? S2 : S1;
    float4 v = *(const float4*)&Wih0[(size_t)src * KDIM + k4];
    float val[4] = {sc * v.x, sc * v.y, sc * v.z, sc * v.w};
    u16 h[4], l[4];
#pragma unroll
    for (int e = 0; e < 4; ++e) hilo(val[e], h[e], l[e]);
    *(ushort4*)&whi[r * KDIM + k4] = make_ushort4(h[0], h[1], h[2], h[3]);
    *(ushort4*)&wlo[r * KDIM + k4] = make_ushort4(l[0], l[1], l[2], l[3]);
  } else if (i < 339968) {                // bsc[3][4096], scaled merged bias
    int f = i - 327680;
    int g = f >> 12, j = f & 4095;
    int src = (g == 0) ? j : (g + 1) * HDIM + j;
    float sc = (g == 1) ? S2 : S1;
    ws[WS_BSC + f] = sc * (bih0[src] + bhh0[src]);
  } else if (i < 348160) {                // c1/c2 packed records (20 floats/j)
    int f = i - 339968;
    const float* Wih = (f < 4096) ? Wih1 : Wih2;
    const float* bih = (f < 4096) ? bih1 : bih2;
    const float* bhh = (f < 4096) ? bhh1 : bhh2;
    const float* Whr = (f < 4096) ? Whr1 : Whr2;
    float* c = ws + ((f < 4096) ? WS_C1 : WS_C2);
    int j = f & 4095;
    float4 wi = *(const float4*)&Wih[(size_t)j * 4];
    float4 wg = *(const float4*)&Wih[(size_t)(2 * HDIM + j) * 4];
    float4 wo = *(const float4*)&Wih[(size_t)(3 * HDIM + j) * 4];
    float* cb = c + j * 20;
    *(float4*)(cb + 0)  = make_float4(S1 * wi.x, S1 * wi.y, S1 * wi.z, S1 * wi.w);
    *(float4*)(cb + 4)  = make_float4(S2 * wg.x, S2 * wg.y, S2 * wg.z, S2 * wg.w);
    *(float4*)(cb + 8)  = make_float4(S1 * wo.x, S1 * wo.y, S1 * wo.z, S1 * wo.w);
    *(float4*)(cb + 12) = make_float4(S1 * (bih[j] + bhh[j]),
                                      S2 * (bih[2 * HDIM + j] + bhh[2 * HDIM + j]),
                                      S1 * (bih[3 * HDIM + j] + bhh[3 * HDIM + j]), 0.f);
    *(float4*)(cb + 16) = make_float4(Whr[j], Whr[HDIM + j], Whr[2 * HDIM + j], Whr[3 * HDIM + j]);
  }
}

// Layer 0: r8 structure (best measured: 78 us) + Pade epilogue.
// Block = 4 waves, covers 256t x 64j (two 128t tiles; W staged once).
// Grid = 32 tbb x 64 jb = 2048. LDS 64KB: W-hi 24K, W-lo 24K, x tile 16K
// (restaged for tile 1 during tile-0 epilogue). Chunk-XOR swizzle -> 0 bank
// conflicts (r7-verified). Projection: butterfly over 16 m-lanes, lane m==0
// stores float4; no atomics. NOTE (r5/r9): do NOT shrink tiles for occupancy
// -- per-block W-DMA + epilogue fixed costs dominate; amortization wins.
__global__ __launch_bounds__(256, 2)
void lstm_layer0_mfma(const u16* __restrict__ xhi, const u16* __restrict__ xlo,
                      const u16* __restrict__ whi, const u16* __restrict__ wlo,
                      const float* __restrict__ bsc, const float* __restrict__ Whr,
                      float* __restrict__ pp) {
  __shared__ __align__(16) char smem[65536];
  u16* lw_hi = (u16*)smem;                 // [192 rows = g*64+j][64 k] swizzled
  u16* lw_lo = (u16*)(smem + 24576);
  u16* lx    = (u16*)(smem + 49152);       // [128 t][64 k] current tile

  const int tid = threadIdx.x;
  const int w = tid >> 6, lane = tid & 63;
  const int m = lane & 15, q = lane >> 4;
  const int jb = blockIdx.x & 63, tbb = blockIdx.x >> 6;
  const int j0 = jb * 64;
  const int t0 = tbb * 256;

  const int r8_ = lane >> 3;
  const int swo = ((lane & 7) ^ r8_) * 8;

  // ---- stage W (48 x 1KB units) + x tile0 (16 units); 16 units/wave
#pragma unroll
  for (int ui = 0; ui < 16; ++ui) {
    const int u = w * 16 + ui;
    const u16* g;
    char* l;
    if (u < 24) {
      g = whi + (size_t)((u >> 3) * HDIM + j0 + (u & 7) * 8 + r8_) * 64 + swo;
      l = smem + u * 1024;
    } else if (u < 48) {
      int uu = u - 24;
      g = wlo + (size_t)((uu >> 3) * HDIM + j0 + (uu & 7) * 8 + r8_) * 64 + swo;
      l = smem + 24576 + uu * 1024;
    } else {
      int uu = u - 48;
      g = xhi + (size_t)(t0 + uu * 8 + r8_) * 64 + swo;
      l = smem + 49152 + uu * 1024;
    }
    gload16(g, l);
  }

  // per-lane constants reused by both tiles (fly under the DMA)
  float whr_v[4][4];
#pragma unroll
  for (int p = 0; p < 4; ++p)
#pragma unroll
    for (int js = 0; js < 4; ++js)
      whr_v[p][js] = Whr[(size_t)p * HDIM + j0 + js * 16 + m];
  float biv[4], bgv[4], bov[4];
#pragma unroll
  for (int js = 0; js < 4; ++js) {
    const int j = j0 + js * 16 + m;
    biv[js] = bsc[j];
    bgv[js] = bsc[HDIM + j];
    bov[js] = bsc[2 * HDIM + j];
  }

  f32x4 acc[2][4][3];
  short8 al[2][2];

  auto zero_acc = [&]() {
#pragma unroll
    for (int ts = 0; ts < 2; ++ts)
#pragma unroll
      for (int js = 0; js < 4; ++js)
#pragma unroll
        for (int g = 0; g < 3; ++g) acc[ts][js][g] = (f32x4){0.f, 0.f, 0.f, 0.f};
  };
  auto load_al = [&](int tt) {
#pragma unroll
    for (int kc = 0; kc < 2; ++kc)
#pragma unroll
      for (int ts = 0; ts < 2; ++ts)
        al[kc][ts] = *(const short8*)&xlo[(size_t)(t0 + tt * 128 + w * 32 + ts * 16 + m) * KDIM + kc * 32 + q * 8];
  };
  auto compute = [&]() {
#pragma unroll
    for (int kc = 0; kc < 2; ++kc) {
      const int cs = ((kc * 4 + q) ^ (m & 7)) * 8;
      short8 ah[2];
#pragma unroll
      for (int ts = 0; ts < 2; ++ts)
        ah[ts] = *(const short8*)&lx[(w * 32 + ts * 16 + m) * 64 + cs];
#pragma unroll
      for (int js = 0; js < 4; ++js) {
#pragma unroll
        for (int g = 0; g < 3; ++g) {
          const int roff = (g * 64 + js * 16 + m) * 64 + cs;
          short8 bh = *(const short8*)&lw_hi[roff];
          short8 bl = *(const short8*)&lw_lo[roff];
#pragma unroll
          for (int ts = 0; ts < 2; ++ts) {
            acc[ts][js][g] = __builtin_amdgcn_mfma_f32_16x16x32_bf16(ah[ts], bh, acc[ts][js][g], 0, 0, 0);
            acc[ts][js][g] = __builtin_amdgcn_mfma_f32_16x16x32_bf16(al[kc][ts], bh, acc[ts][js][g], 0, 0, 0);
            acc[ts][js][g] = __builtin_amdgcn_mfma_f32_16x16x32_bf16(ah[ts], bl, acc[ts][js][g], 0, 0, 0);
          }
        }
      }
    }
  };
  auto act_proj = [&](int tt) {
    float hreg[2][4][4];
#pragma unroll
    for (int js = 0; js < 4; ++js) {
#pragma unroll
      for (int ts = 0; ts < 2; ++ts) {
#pragma unroll
        for (int r = 0; r < 4; ++r) {
          float ea = EXP2(acc[ts][js][0][r] + biv[js]);       // e^-i
          float eb = EXP2(acc[ts][js][1][r] + bgv[js]);       // e^-2g
          float c = (1.0f - eb) * rcpf((1.0f + ea) * (1.0f + eb));  // sig(i)tanh(g)
          float ec = EXP2(acc[ts][js][2][r] + bov[js]);       // e^-o
          hreg[ts][js][r] = h_merge(c, ec);                   // tanh(c)sig(o)
        }
      }
    }
    // projection partial over this lane's 4 js, then butterfly over 16 m-lanes
#pragma unroll
    for (int ts = 0; ts < 2; ++ts) {
#pragma unroll
      for (int r = 0; r < 4; ++r) {
        float pv[4];
#pragma unroll
        for (int p = 0; p < 4; ++p) {
          float s = 0.f;
#pragma unroll
          for (int js = 0; js < 4; ++js) s = fmaf(hreg[ts][js][r], whr_v[p][js], s);
#pragma unroll
          for (int ofs = 1; ofs < 16; ofs <<= 1) s += __shfl_xor(s, ofs, 16);
          pv[p] = s;
        }
        if (m == 0) {
          const int t = t0 + tt * 128 + w * 32 + ts * 16 + q * 4 + r;
          *(float4*)&pp[((size_t)jb * TSTEPS + t) * PDIM] = make_float4(pv[0], pv[1], pv[2], pv[3]);
        }
      }
    }
  };

  // ---- tile 0
  load_al(0);
  zero_acc();
  __syncthreads();                 // drain W + x0 DMA
  compute();
  __syncthreads();                 // all x-region reads done
  // ---- stage x tile1 (16 units, 4/wave) while tile-0 epilogue runs
#pragma unroll
  for (int ui = 0; ui < 4; ++ui) {
    const int u = w * 4 + ui;
    gload16(xhi + (size_t)(t0 + 128 + u * 8 + r8_) * 64 + swo, smem + 49152 + u * 1024);
  }
  load_al(1);
  act_proj(0);
  zero_acc();
  __syncthreads();                 // drain x1 DMA
  compute();
  act_proj(1);
}

// Reduce 64 partial slices -> y[t][4]; one thread per (t,p), fully coalesced.
__global__ void reduce64(const float* __restrict__ pp, float* __restrict__ y) {
  const int i = blockIdx.x * 256 + threadIdx.x;   // 0..32767 = t*4 + p
  float s = 0.f;
#pragma unroll 16
  for (int k = 0; k < 64; ++k) s += pp[(size_t)k * (TSTEPS * PDIM) + i];
  y[i] = s;
}

// Layers 1-2 (K=4): LDS records, 2 timesteps/thread, explicit REGISTER
// PREFETCH of record jj+1 while computing jj (overlaps ds_read latency with
// the act chain), and NO __launch_bounds__ cap -- prior rounds' (256,8)/(256,4)
// caps likely forced scratch spills (smalls pinned at ~70us across 6 designs
// vs ~20us VALU floor). LDS padded to 65 records so prefetch needs no branch.
// Grid = 16 tchunks x 64 jsplits = 1024; plain partial stores.
__global__ void lstm_small(const float* __restrict__ xin, const float* __restrict__ cpk,
                           float* __restrict__ pp) {
  __shared__ __align__(16) float rec[1300];       // 65 slots x 20 floats
  const int tid = threadIdx.x;
  const int tc = blockIdx.x >> 6;                 // 0..15
  const int jsp = blockIdx.x & 63;                // 0..63
  const int j0 = jsp * 64;

  for (int i = tid; i < 320; i += 256)
    ((float4*)rec)[i] = ((const float4*)(cpk + (size_t)j0 * 20))[i];

  const int ta = tc * 512 + tid;
  const int tb2 = ta + 256;
  float4 xa = ((const float4*)xin)[ta];
  float4 xb = ((const float4*)xin)[tb2];
  float a0 = 0.f, a1 = 0.f, a2 = 0.f, a3 = 0.f;
  float b0 = 0.f, b1 = 0.f, b2 = 0.f, b3 = 0.f;
  __syncthreads();

  float4 wi = *(const float4*)(rec + 0);
  float4 wg = *(const float4*)(rec + 4);
  float4 wo = *(const float4*)(rec + 8);
  float4 bb = *(const float4*)(rec + 12);
  float4 wr = *(const float4*)(rec + 16);

#pragma unroll 2
  for (int jj = 0; jj < 64; ++jj) {
    // prefetch record jj+1 (slot 64 is a harmless dummy read)
    const float* nb = rec + (jj + 1) * 20;
    float4 nwi = *(const float4*)(nb + 0);
    float4 nwg = *(const float4*)(nb + 4);
    float4 nwo = *(const float4*)(nb + 8);
    float4 nbb = *(const float4*)(nb + 12);
    float4 nwr = *(const float4*)(nb + 16);
    // timestep a
    float gi = bb.x, gg = bb.y, go = bb.z;
    gi = fmaf(xa.x, wi.x, gi); gi = fmaf(xa.y, wi.y, gi);
    gi = fmaf(xa.z, wi.z, gi); gi = fmaf(xa.w, wi.w, gi);
    gg = fmaf(xa.x, wg.x, gg); gg = fmaf(xa.y, wg.y, gg);
    gg = fmaf(xa.z, wg.z, gg); gg = fmaf(xa.w, wg.w, gg);
    go = fmaf(xa.x, wo.x, go); go = fmaf(xa.y, wo.y, go);
    go = fmaf(xa.z, wo.z, go); go = fmaf(xa.w, wo.w, go);
    float ea = EXP2(gi), eb = EXP2(gg);
    float c = (1.0f - eb) * rcpf((1.0f + ea) * (1.0f + eb));
    float h = h_merge(c, EXP2(go));
    a0 = fmaf(h, wr.x, a0); a1 = fmaf(h, wr.y, a1);
    a2 = fmaf(h, wr.z, a2); a3 = fmaf(h, wr.w, a3);
    // timestep b
    gi = bb.x; gg = bb.y; go = bb.z;
    gi = fmaf(xb.x, wi.x, gi); gi = fmaf(xb.y, wi.y, gi);
    gi = fmaf(xb.z, wi.z, gi); gi = fmaf(xb.w, wi.w, gi);
    gg = fmaf(xb.x, wg.x, gg); gg = fmaf(xb.y, wg.y, gg);
    gg = fmaf(xb.z, wg.z, gg); gg = fmaf(xb.w, wg.w, gg);
    go = fmaf(xb.x, wo.x, go); go = fmaf(xb.y, wo.y, go);
    go = fmaf(xb.z, wo.z, go); go = fmaf(xb.w, wo.w, go);
    ea = EXP2(gi); eb = EXP2(gg);
    c = (1.0f - eb) * rcpf((1.0f + ea) * (1.0f + eb));
    h = h_merge(c, EXP2(go));
    b0 = fmaf(h, wr.x, b0); b1 = fmaf(h, wr.y, b1);
    b2 = fmaf(h, wr.z, b2); b3 = fmaf(h, wr.w, b3);
    // rotate prefetched record in
    wi = nwi; wg = nwg; wo = nwo; bb = nbb; wr = nwr;
  }

  ((float4*)pp)[(size_t)jsp * TSTEPS + ta]  = make_float4(a0, a1, a2, a3);
  ((float4*)pp)[(size_t)jsp * TSTEPS + tb2] = make_float4(b0, b1, b2, b3);
}

extern "C" void kernel_launch(void* const* d_in, const int* in_sizes, int n_in,
                              void* d_out, int out_size, void* d_ws, size_t ws_size,
                              hipStream_t stream) {
  const float* x    = (const float*)d_in[0];
  const float* Wih0 = (const float*)d_in[1];
  const float* bih0 = (const float*)d_in[3];
  const float* bhh0 = (const float*)d_in[4];
  const float* Whr0 = (const float*)d_in[5];
  const float* Wih1 = (const float*)d_in[6];
  const float* bih1 = (const float*)d_in[8];
  const float* bhh1 = (const float*)d_in[9];
  const float* Whr1 = (const float*)d_in[10];
  const float* Wih2 = (const float*)d_in[11];
  const float* bih2 = (const float*)d_in[13];
  const float* bhh2 = (const float*)d_in[14];
  const float* Whr2 = (const float*)d_in[15];
  float* out = (float*)d_out;
  float* ws = (float*)d_ws;
  float* pp = ws + WS_PP;

  prep_kernel<<<dim3(1360), dim3(256), 0, stream>>>(
      x, Wih0, bih0, bhh0, Wih1, bih1, bhh1, Whr1, Wih2, bih2, bhh2, Whr2, ws);

  lstm_layer0_mfma<<<dim3(2048), dim3(256), 0, stream>>>(
      (const u16*)(ws + WS_XHI), (const u16*)(ws + WS_XLO),
      (const u16*)(ws + WS_WHI), (const u16*)(ws + WS_WLO),
      ws + WS_BSC, Whr0, pp);
  reduce64<<<dim3(128), dim3(256), 0, stream>>>(pp, ws + WS_Y0);

  lstm_small<<<dim3(1024), dim3(256), 0, stream>>>(ws + WS_Y0, ws + WS_C1, pp);
  reduce64<<<dim3(128), dim3(256), 0, stream>>>(pp, ws + WS_Y1);

  lstm_small<<<dim3(1024), dim3(256), 0, stream>>>(ws + WS_Y1, ws + WS_C2, pp);
  reduce64<<<dim3(128), dim3(256), 0, stream>>>(pp, out);
}